// Round 1
// baseline (618.822 us; speedup 1.0000x reference)
//
#include <hip/hip_runtime.h>

#define N_NODES 100000
#define N_EDGES 3200000
#define EMBED_DIM 64
#define BATCH 16384

// Workspace layout (bytes):
//   [0, 400000)        deg -> dinv (N floats)
//   [400000, 800000)   needed flags (N ints)
//   [800000, 26400000) agg (N*64 floats)
#define WS_DEG_OFF 0
#define WS_NEEDED_OFF 400000
#define WS_AGG_OFF 800000

__global__ void k_init(float4* ws4, int n4) {
    int i = blockIdx.x * blockDim.x + threadIdx.x;
    int stride = gridDim.x * blockDim.x;
    float4 z = make_float4(0.f, 0.f, 0.f, 0.f);
    for (; i < n4; i += stride) ws4[i] = z;
}

__global__ void k_flags(const int* __restrict__ pairs, int* __restrict__ needed) {
    int i = blockIdx.x * blockDim.x + threadIdx.x;
    if (i < 2 * BATCH) needed[pairs[i]] = 1;
}

__global__ void k_deg(const int* __restrict__ dst, float* __restrict__ deg) {
    int i = blockIdx.x * blockDim.x + threadIdx.x;
    int stride = gridDim.x * blockDim.x;
    for (; i < N_EDGES; i += stride) atomicAdd(&deg[dst[i]], 1.0f);
}

__global__ void k_dinv(float* __restrict__ deg) {
    int i = blockIdx.x * blockDim.x + threadIdx.x;
    if (i < N_NODES) deg[i] = rsqrtf(deg[i] + 1.0f);
}

// One wave (64 lanes) per edge; lane = embedding dim. dst/src are wave-uniform
// so the needed-check branch is non-divergent and the gather/atomic are fully
// coalesced 256B accesses.
__global__ void k_edges(const int* __restrict__ src_arr, const int* __restrict__ dst_arr,
                        const float* __restrict__ w, const float* __restrict__ dinv,
                        const int* __restrict__ needed, float* __restrict__ agg) {
    int wave = (blockIdx.x * blockDim.x + threadIdx.x) >> 6;
    int lane = threadIdx.x & 63;
    int nWaves = (gridDim.x * blockDim.x) >> 6;
    for (int e = wave; e < N_EDGES; e += nWaves) {
        int d = dst_arr[e];
        if (!needed[d]) continue;
        int s = src_arr[e];
        float norm = dinv[s] * dinv[d];
        atomicAdd(&agg[d * EMBED_DIM + lane], w[s * EMBED_DIM + lane] * norm);
    }
}

// One wave per interaction pair: emb = agg + W * (1/deg) + bias; out = lin + dot.
__global__ void k_final(const int* __restrict__ pairs, const float* __restrict__ w,
                        const float* __restrict__ bias, const float* __restrict__ lw,
                        const float* __restrict__ lb, const float* __restrict__ dinv,
                        const float* __restrict__ agg, float* __restrict__ out) {
    int wave = (blockIdx.x * blockDim.x + threadIdx.x) >> 6;
    int lane = threadIdx.x & 63;
    if (wave >= BATCH) return;
    int a = pairs[wave * 2 + 0];
    int b = pairs[wave * 2 + 1];
    float da = dinv[a], db = dinv[b];
    float bi = bias[lane];
    float ea = agg[a * EMBED_DIM + lane] + w[a * EMBED_DIM + lane] * (da * da) + bi;
    float eb = agg[b * EMBED_DIM + lane] + w[b * EMBED_DIM + lane] * (db * db) + bi;
    float prod = ea * eb;
#pragma unroll
    for (int m = 32; m >= 1; m >>= 1) prod += __shfl_xor(prod, m, 64);
    if (lane == 0) out[wave] = lw[a] + lw[b] + lb[0] + prod;
}

extern "C" void kernel_launch(void* const* d_in, const int* in_sizes, int n_in,
                              void* d_out, int out_size, void* d_ws, size_t ws_size,
                              hipStream_t stream) {
    const float* gcn_weight   = (const float*)d_in[0];   // [N, 64]
    const float* gcn_bias     = (const float*)d_in[1];   // [64]
    const float* linear_weight= (const float*)d_in[2];   // [N, 1]
    const float* linear_bias  = (const float*)d_in[3];   // [1]
    const int*   edge_index   = (const int*)d_in[4];     // [2, E] row-major
    const int*   pairs        = (const int*)d_in[5];     // [B, 2] row-major
    float* out = (float*)d_out;

    char* ws = (char*)d_ws;
    float* deg    = (float*)(ws + WS_DEG_OFF);     // becomes dinv after k_dinv
    int*   needed = (int*)  (ws + WS_NEEDED_OFF);
    float* agg    = (float*)(ws + WS_AGG_OFF);

    const int* src_arr = edge_index;
    const int* dst_arr = edge_index + N_EDGES;

    // total zeroed region: N*66 floats = 6,600,000 floats = 1,650,000 float4
    k_init<<<4096, 256, 0, stream>>>((float4*)ws, 1650000);
    k_flags<<<(2 * BATCH + 255) / 256, 256, 0, stream>>>(pairs, needed);
    k_deg<<<2048, 256, 0, stream>>>(dst_arr, deg);
    k_dinv<<<(N_NODES + 255) / 256, 256, 0, stream>>>(deg);
    k_edges<<<2048, 256, 0, stream>>>(src_arr, dst_arr, gcn_weight, deg, needed, agg);
    k_final<<<BATCH / 4, 256, 0, stream>>>(pairs, gcn_weight, gcn_bias, linear_weight,
                                           linear_bias, deg, agg, out);
}

// Round 2
// 347.992 us; speedup vs baseline: 1.7783x; 1.7783x over previous
//
#include <hip/hip_runtime.h>

#define N_NODES 100000
#define N_EDGES 3200000
#define EMBED_DIM 64
#define BATCH 16384
#define MAX_SLOTS 32768   // <= 2*BATCH distinct nodes can appear in pairs

// Workspace layout (byte offsets). ws_size >= 26.4 MB (proven by round 1).
//   cnt      @ 0          : 100000 ints  (in-degree counts, dst side)
//   slot     @ 400000     : 100000 ints  (0 = unused; else slot_id+1)
//   cursor   @ 800000     : 100000 ints  (bin write cursors; after scatter = end)
//   dinv     @ 1200000    : 100000 floats (rsqrt(deg+1))
//   nodelist @ 1600000    : 32768 ints   (slot -> node)
//   counters @ 2000000    : [0]=nSlots, [1]=binTotal
//   bins     @ 2097152    : up to 3.2M ints (src ids of needed edges)
//   emb      @ 14897152   : 32768 x 64 floats (compacted node embeddings)
#define OFF_CNT      0
#define OFF_SLOT     400000
#define OFF_CURSOR   800000
#define OFF_DINV     1200000
#define OFF_NODELIST 1600000
#define OFF_COUNTERS 2000000
#define OFF_BINS     2097152
#define OFF_EMB      14897152

__global__ void k_init(float4* ws4, int n4) {
    int i = blockIdx.x * blockDim.x + threadIdx.x;
    int stride = gridDim.x * blockDim.x;
    float4 z = make_float4(0.f, 0.f, 0.f, 0.f);
    for (; i < n4; i += stride) ws4[i] = z;
}

__global__ void k_flags(const int* __restrict__ pairs, int* __restrict__ slot) {
    int i = blockIdx.x * blockDim.x + threadIdx.x;
    if (i < 2 * BATCH) slot[pairs[i]] = 1;   // benign races: all write 1
}

__global__ void k_compact(int* __restrict__ slot, int* __restrict__ nodelist,
                          int* __restrict__ counters) {
    int n = blockIdx.x * blockDim.x + threadIdx.x;
    if (n >= N_NODES) return;
    if (slot[n]) {
        int s = atomicAdd(&counters[0], 1);
        slot[n] = s + 1;
        nodelist[s] = n;
    }
}

__global__ void k_count(const int* __restrict__ dst, int* __restrict__ cnt) {
    int i = blockIdx.x * blockDim.x + threadIdx.x;
    int stride = gridDim.x * blockDim.x;
    for (; i < N_EDGES; i += stride) atomicAdd(&cnt[dst[i]], 1);
}

__global__ void k_dinv_alloc(const int* __restrict__ cnt, const int* __restrict__ slot,
                             float* __restrict__ dinv, int* __restrict__ cursor,
                             int* __restrict__ counters) {
    int n = blockIdx.x * blockDim.x + threadIdx.x;
    if (n >= N_NODES) return;
    int c = cnt[n];
    dinv[n] = rsqrtf((float)c + 1.0f);
    if (slot[n]) cursor[n] = atomicAdd(&counters[1], c);
}

__global__ void k_scatter(const int* __restrict__ src, const int* __restrict__ dst,
                          const int* __restrict__ slot, int* __restrict__ cursor,
                          int* __restrict__ bins) {
    int i = blockIdx.x * blockDim.x + threadIdx.x;
    int stride = gridDim.x * blockDim.x;
    for (; i < N_EDGES; i += stride) {
        int d = dst[i];
        if (slot[d]) {
            int p = atomicAdd(&cursor[d], 1);
            bins[p] = src[i];
        }
    }
}

// One wave per needed node (slot). lane = dim. Register accumulation, no atomics.
// norm = dinv[s]*dinv[d]; dinv[d] factored out of the sum. Self-loop + bias fused.
__global__ void k_gather(const int* __restrict__ nodelist, const int* __restrict__ cnt,
                         const int* __restrict__ cursor, const int* __restrict__ bins,
                         const float* __restrict__ w, const float* __restrict__ dinv,
                         const float* __restrict__ bias, const int* __restrict__ counters,
                         float* __restrict__ emb) {
    int s = (blockIdx.x * blockDim.x + threadIdx.x) >> 6;
    int lane = threadIdx.x & 63;
    if (s >= counters[0]) return;
    int n = nodelist[s];
    int c = cnt[n];
    int end = cursor[n];      // post-scatter: start + c
    int beg = end - c;
    float acc = 0.f;
    int j = beg;
    for (; j + 4 <= end; j += 4) {
        int s0 = bins[j], s1 = bins[j + 1], s2 = bins[j + 2], s3 = bins[j + 3];
        float d0 = dinv[s0], d1 = dinv[s1], d2 = dinv[s2], d3 = dinv[s3];
        acc += w[(s0 << 6) + lane] * d0;
        acc += w[(s1 << 6) + lane] * d1;
        acc += w[(s2 << 6) + lane] * d2;
        acc += w[(s3 << 6) + lane] * d3;
    }
    for (; j < end; ++j) {
        int si = bins[j];
        acc += w[(si << 6) + lane] * dinv[si];
    }
    float dn = dinv[n];
    emb[(s << 6) + lane] = acc * dn + w[(n << 6) + lane] * (dn * dn) + bias[lane];
}

// One wave per pair: FM pairwise term == dot(emb_a, emb_b). Add linear terms.
__global__ void k_final(const int* __restrict__ pairs, const int* __restrict__ slot,
                        const float* __restrict__ emb, const float* __restrict__ lw,
                        const float* __restrict__ lb, float* __restrict__ out) {
    int p = (blockIdx.x * blockDim.x + threadIdx.x) >> 6;
    int lane = threadIdx.x & 63;
    if (p >= BATCH) return;
    int a = pairs[p * 2 + 0];
    int b = pairs[p * 2 + 1];
    int sa = slot[a] - 1;
    int sb = slot[b] - 1;
    float ea = emb[(sa << 6) + lane];
    float eb = emb[(sb << 6) + lane];
    float prod = ea * eb;
#pragma unroll
    for (int m = 32; m >= 1; m >>= 1) prod += __shfl_xor(prod, m, 64);
    if (lane == 0) out[p] = lw[a] + lw[b] + lb[0] + prod;
}

extern "C" void kernel_launch(void* const* d_in, const int* in_sizes, int n_in,
                              void* d_out, int out_size, void* d_ws, size_t ws_size,
                              hipStream_t stream) {
    const float* gcn_weight    = (const float*)d_in[0];   // [N, 64]
    const float* gcn_bias      = (const float*)d_in[1];   // [64]
    const float* linear_weight = (const float*)d_in[2];   // [N, 1]
    const float* linear_bias   = (const float*)d_in[3];   // [1]
    const int*   edge_index    = (const int*)d_in[4];     // [2, E]
    const int*   pairs         = (const int*)d_in[5];     // [B, 2]
    float* out = (float*)d_out;

    char* ws = (char*)d_ws;
    int*   cnt      = (int*)  (ws + OFF_CNT);
    int*   slot     = (int*)  (ws + OFF_SLOT);
    int*   cursor   = (int*)  (ws + OFF_CURSOR);
    float* dinv     = (float*)(ws + OFF_DINV);
    int*   nodelist = (int*)  (ws + OFF_NODELIST);
    int*   counters = (int*)  (ws + OFF_COUNTERS);
    int*   bins     = (int*)  (ws + OFF_BINS);
    float* emb      = (float*)(ws + OFF_EMB);

    const int* src_arr = edge_index;
    const int* dst_arr = edge_index + N_EDGES;

    // Zero the metadata region [0, 2 MiB): cnt, slot, cursor, dinv, nodelist, counters.
    k_init<<<512, 256, 0, stream>>>((float4*)ws, 131072);
    k_flags<<<(2 * BATCH + 255) / 256, 256, 0, stream>>>(pairs, slot);
    k_compact<<<(N_NODES + 255) / 256, 256, 0, stream>>>(slot, nodelist, counters);
    k_count<<<2048, 256, 0, stream>>>(dst_arr, cnt);
    k_dinv_alloc<<<(N_NODES + 255) / 256, 256, 0, stream>>>(cnt, slot, dinv, cursor, counters);
    k_scatter<<<2048, 256, 0, stream>>>(src_arr, dst_arr, slot, cursor, bins);
    k_gather<<<MAX_SLOTS / 4, 256, 0, stream>>>(nodelist, cnt, cursor, bins, gcn_weight,
                                                dinv, gcn_bias, counters, emb);
    k_final<<<BATCH / 4, 256, 0, stream>>>(pairs, slot, emb, linear_weight, linear_bias, out);
}

// Round 3
// 267.597 us; speedup vs baseline: 2.3125x; 1.3004x over previous
//
#include <hip/hip_runtime.h>

#define N_NODES 100000
#define N_EDGES 3200000
#define EMBED_DIM 64
#define BATCH 16384
#define MAX_SLOTS 32768

// Histogram partitioning: 7 partitions x 14336 bins (56 KB LDS), 32 edge slices.
#define HP 7
#define HNP 14336
#define HG 32
#define EDGES_PER_SLICE (N_EDGES / HG)   // 100000

// Workspace layout (byte offsets), peak 22,964,800 B (< 23.3 MB proven in R2):
//   slot     @ 0        : 100000 ints (0 = unused, else slot_id+1)
//   counters @ 400000   : 16 ints  ([0]=nSlots, [1]=binTotal)
//   cnt      @ 400064   : 100000 ints (in-degree)
//   cursor   @ 800064   : 100000 ints (bin cursors; post-scatter = end)
//   dinv     @ 1200064  : 100000 floats (rsqrt(deg+1))
//   nodelist @ 1600064  : 32768 ints (slot -> node)
//   partials @ 1731136  : 224 x 14336 ints = 12,845,056 B  (dead after reduce)
//   bins     @ 1731136  : OVERLAYS partials (src ids of needed edges)
//   emb      @ 14576192 : 32768 x 64 floats
#define OFF_SLOT     0
#define OFF_COUNTERS 400000
#define OFF_CNT      400064
#define OFF_CURSOR   800064
#define OFF_DINV     1200064
#define OFF_NODELIST 1600064
#define OFF_PARTIALS 1731136
#define OFF_BINS     1731136
#define OFF_EMB      14576192

__global__ void k_init(int4* slot4, int* counters) {
    int i = blockIdx.x * blockDim.x + threadIdx.x;
    int stride = gridDim.x * blockDim.x;
    for (int j = i; j < 25000; j += stride) slot4[j] = make_int4(0, 0, 0, 0);
    if (i < 16) counters[i] = 0;
}

__global__ void k_flags(const int* __restrict__ pairs, int* __restrict__ slot) {
    int i = blockIdx.x * blockDim.x + threadIdx.x;
    if (i < 2 * BATCH) slot[pairs[i]] = 1;   // benign races: all write 1
}

// Wave-aggregated compaction: one atomic per wave instead of per thread.
__global__ void k_compact(int* __restrict__ slot, int* __restrict__ nodelist,
                          int* __restrict__ counters) {
    int n = blockIdx.x * blockDim.x + threadIdx.x;
    int lane = threadIdx.x & 63;
    int want = (n < N_NODES && slot[n]) ? 1 : 0;
    int incl = want;
#pragma unroll
    for (int d = 1; d < 64; d <<= 1) {
        int t = __shfl_up(incl, d, 64);
        if (lane >= d) incl += t;
    }
    int total = __shfl(incl, 63, 64);
    int base = 0;
    if (lane == 63 && total > 0) base = atomicAdd(&counters[0], total);
    base = __shfl(base, 63, 64);
    if (want) {
        int s = base + incl - 1;   // exclusive prefix
        slot[n] = s + 1;
        nodelist[s] = n;
    }
}

// LDS-partitioned degree histogram: zero device atomics.
__global__ void k_hist(const int* __restrict__ dst, int* __restrict__ partials) {
    __shared__ int h[HNP];
    int b = blockIdx.x;            // 0..HP*HG-1
    int p = b % HP, g = b / HP;    // partition, edge-slice
    int base = p * HNP;
    for (int i = threadIdx.x; i < HNP; i += blockDim.x) h[i] = 0;
    __syncthreads();
    const int4* d4 = (const int4*)(dst + g * EDGES_PER_SLICE);
    for (int i = threadIdx.x; i < EDGES_PER_SLICE / 4; i += blockDim.x) {
        int4 v = d4[i];
        int t;
        t = v.x - base; if ((unsigned)t < (unsigned)HNP) atomicAdd(&h[t], 1);
        t = v.y - base; if ((unsigned)t < (unsigned)HNP) atomicAdd(&h[t], 1);
        t = v.z - base; if ((unsigned)t < (unsigned)HNP) atomicAdd(&h[t], 1);
        t = v.w - base; if ((unsigned)t < (unsigned)HNP) atomicAdd(&h[t], 1);
    }
    __syncthreads();
    int* out = partials + b * HNP;
    for (int i = threadIdx.x; i < HNP; i += blockDim.x) out[i] = h[i];
}

// Sum partials -> cnt, dinv; wave-aggregated bin-space allocation for needed nodes.
__global__ void k_reduce_alloc(const int* __restrict__ partials, const int* __restrict__ slot,
                               int* __restrict__ cnt, float* __restrict__ dinv,
                               int* __restrict__ cursor, int* __restrict__ counters) {
    int n = blockIdx.x * blockDim.x + threadIdx.x;
    int lane = threadIdx.x & 63;
    int c = 0;
    bool valid = (n < N_NODES);
    if (valid) {
        int p = n / HNP, off = n - p * HNP;
        const int* q = partials + p * HNP + off;
#pragma unroll
        for (int g = 0; g < HG; ++g) c += q[g * HP * HNP];
        cnt[n] = c;
        dinv[n] = rsqrtf((float)c + 1.0f);
    }
    int want = (valid && slot[n]) ? c : 0;
    int incl = want;
#pragma unroll
    for (int d = 1; d < 64; d <<= 1) {
        int t = __shfl_up(incl, d, 64);
        if (lane >= d) incl += t;
    }
    int total = __shfl(incl, 63, 64);
    int base = 0;
    if (lane == 63 && total > 0) base = atomicAdd(&counters[1], total);
    base = __shfl(base, 63, 64);
    if (valid && slot[n]) cursor[n] = base + incl - want;
}

__global__ void k_scatter(const int* __restrict__ src, const int* __restrict__ dst,
                          const int* __restrict__ slot, int* __restrict__ cursor,
                          int* __restrict__ bins) {
    int i = blockIdx.x * blockDim.x + threadIdx.x;
    int stride = gridDim.x * blockDim.x;
    for (; i < N_EDGES; i += stride) {
        int d = dst[i];
        if (slot[d]) {
            int p = atomicAdd(&cursor[d], 1);
            bins[p] = src[i];
        }
    }
}

// One wave per needed node. lane = dim. Register accumulation, no atomics.
__global__ void k_gather(const int* __restrict__ nodelist, const int* __restrict__ cnt,
                         const int* __restrict__ cursor, const int* __restrict__ bins,
                         const float* __restrict__ w, const float* __restrict__ dinv,
                         const float* __restrict__ bias, const int* __restrict__ counters,
                         float* __restrict__ emb) {
    int s = (blockIdx.x * blockDim.x + threadIdx.x) >> 6;
    int lane = threadIdx.x & 63;
    if (s >= counters[0]) return;
    int n = nodelist[s];
    int c = cnt[n];
    int end = cursor[n];      // post-scatter: start + c
    int beg = end - c;
    float acc = 0.f;
    int j = beg;
    for (; j + 4 <= end; j += 4) {
        int s0 = bins[j], s1 = bins[j + 1], s2 = bins[j + 2], s3 = bins[j + 3];
        float d0 = dinv[s0], d1 = dinv[s1], d2 = dinv[s2], d3 = dinv[s3];
        acc += w[(s0 << 6) + lane] * d0;
        acc += w[(s1 << 6) + lane] * d1;
        acc += w[(s2 << 6) + lane] * d2;
        acc += w[(s3 << 6) + lane] * d3;
    }
    for (; j < end; ++j) {
        int si = bins[j];
        acc += w[(si << 6) + lane] * dinv[si];
    }
    float dn = dinv[n];
    emb[(s << 6) + lane] = acc * dn + w[(n << 6) + lane] * (dn * dn) + bias[lane];
}

// One wave per pair: FM pairwise term == dot(emb_a, emb_b). Add linear terms.
__global__ void k_final(const int* __restrict__ pairs, const int* __restrict__ slot,
                        const float* __restrict__ emb, const float* __restrict__ lw,
                        const float* __restrict__ lb, float* __restrict__ out) {
    int p = (blockIdx.x * blockDim.x + threadIdx.x) >> 6;
    int lane = threadIdx.x & 63;
    if (p >= BATCH) return;
    int a = pairs[p * 2 + 0];
    int b = pairs[p * 2 + 1];
    int sa = slot[a] - 1;
    int sb = slot[b] - 1;
    float ea = emb[(sa << 6) + lane];
    float eb = emb[(sb << 6) + lane];
    float prod = ea * eb;
#pragma unroll
    for (int m = 32; m >= 1; m >>= 1) prod += __shfl_xor(prod, m, 64);
    if (lane == 0) out[p] = lw[a] + lw[b] + lb[0] + prod;
}

extern "C" void kernel_launch(void* const* d_in, const int* in_sizes, int n_in,
                              void* d_out, int out_size, void* d_ws, size_t ws_size,
                              hipStream_t stream) {
    const float* gcn_weight    = (const float*)d_in[0];   // [N, 64]
    const float* gcn_bias      = (const float*)d_in[1];   // [64]
    const float* linear_weight = (const float*)d_in[2];   // [N, 1]
    const float* linear_bias   = (const float*)d_in[3];   // [1]
    const int*   edge_index    = (const int*)d_in[4];     // [2, E]
    const int*   pairs         = (const int*)d_in[5];     // [B, 2]
    float* out = (float*)d_out;

    char* ws = (char*)d_ws;
    int*   slot     = (int*)  (ws + OFF_SLOT);
    int*   counters = (int*)  (ws + OFF_COUNTERS);
    int*   cnt      = (int*)  (ws + OFF_CNT);
    int*   cursor   = (int*)  (ws + OFF_CURSOR);
    float* dinv     = (float*)(ws + OFF_DINV);
    int*   nodelist = (int*)  (ws + OFF_NODELIST);
    int*   partials = (int*)  (ws + OFF_PARTIALS);
    int*   bins     = (int*)  (ws + OFF_BINS);
    float* emb      = (float*)(ws + OFF_EMB);

    const int* src_arr = edge_index;
    const int* dst_arr = edge_index + N_EDGES;

    k_init<<<98, 256, 0, stream>>>((int4*)(ws + OFF_SLOT), counters);
    k_flags<<<(2 * BATCH + 255) / 256, 256, 0, stream>>>(pairs, slot);
    k_compact<<<(N_NODES + 255) / 256, 256, 0, stream>>>(slot, nodelist, counters);
    k_hist<<<HP * HG, 256, 0, stream>>>(dst_arr, partials);
    k_reduce_alloc<<<(N_NODES + 255) / 256, 256, 0, stream>>>(partials, slot, cnt, dinv,
                                                              cursor, counters);
    k_scatter<<<2048, 256, 0, stream>>>(src_arr, dst_arr, slot, cursor, bins);
    k_gather<<<MAX_SLOTS / 4, 256, 0, stream>>>(nodelist, cnt, cursor, bins, gcn_weight,
                                                dinv, gcn_bias, counters, emb);
    k_final<<<BATCH / 4, 256, 0, stream>>>(pairs, slot, emb, linear_weight, linear_bias, out);
}